// Round 3
// baseline (289.282 us; speedup 1.0000x reference)
//
#include <hip/hip_runtime.h>
#include <hip/hip_bf16.h>
#include <math.h>

// Shapes (fixed by the problem)
#define BB 2
#define TT 2048
#define DD 512
#define HH 8
#define HD 64
#define FF_ 2048
#define M4 4096  // BB*TT

typedef __attribute__((ext_vector_type(8))) __bf16 bf16x8;
typedef __attribute__((ext_vector_type(4))) float floatx4;

__device__ __forceinline__ unsigned short f2bf(float f) {
  unsigned u = __builtin_bit_cast(unsigned, f);
  u += 0x7fffu + ((u >> 16) & 1u);  // RNE
  return (unsigned short)(u >> 16);
}

__device__ __forceinline__ bf16x8 frag16(const unsigned short* p) {
  return __builtin_bit_cast(bf16x8, *(const uint4*)p);
}

__device__ __forceinline__ floatx4 mfma_bf16(bf16x8 a, bf16x8 b, floatx4 c) {
  return __builtin_amdgcn_mfma_f32_16x16x32_bf16(a, b, c, 0, 0, 0);
}

// ---------------- all 6 weight transposes in ONE launch: src (K,N) f32 -> dst (N,K) bf16
__global__ void transpose_all(const float* __restrict__ wq, const float* __restrict__ wk,
                              const float* __restrict__ wv, const float* __restrict__ wo,
                              const float* __restrict__ w1, const float* __restrict__ w2,
                              unsigned short* __restrict__ wqkvT, unsigned short* __restrict__ woT,
                              unsigned short* __restrict__ w1T, unsigned short* __restrict__ w2T) {
  __shared__ float tile[32][33];
  const int bid = blockIdx.x;
  const float* src;
  unsigned short* dst;
  int Kd = 512, Nd = 512, tIdx;
  if (bid < 256) { src = wq; dst = wqkvT; tIdx = bid; }
  else if (bid < 512) { src = wk; dst = wqkvT + 512 * 512; tIdx = bid - 256; }
  else if (bid < 768) { src = wv; dst = wqkvT + 2 * 512 * 512; tIdx = bid - 512; }
  else if (bid < 1024) { src = wo; dst = woT; tIdx = bid - 768; }
  else if (bid < 2048) { src = w1; dst = w1T; Nd = 2048; tIdx = bid - 1024; }
  else { src = w2; dst = w2T; Kd = 2048; tIdx = bid - 2048; }
  const int nTilesX = Nd / 32;
  const int n0 = (tIdx % nTilesX) * 32, k0 = (tIdx / nTilesX) * 32;
  for (int i = threadIdx.y; i < 32; i += 8)
    tile[i][threadIdx.x] = src[(size_t)(k0 + i) * Nd + n0 + threadIdx.x];
  __syncthreads();
  for (int i = threadIdx.y; i < 32; i += 8)
    dst[(size_t)(n0 + i) * Kd + k0 + threadIdx.x] = f2bf(tile[threadIdx.x][i]);
}

// ---------------- LayerNorm: fp32 (rows of 512) -> bf16
__global__ __launch_bounds__(128) void ln_kernel(const float* __restrict__ src,
                                                 const float* __restrict__ gg,
                                                 const float* __restrict__ bb,
                                                 unsigned short* __restrict__ dst) {
  const int row = blockIdx.x;
  const int t = threadIdx.x;
  float4 v = ((const float4*)(src + (size_t)row * DD))[t];
  float s = v.x + v.y + v.z + v.w;
  float ss = v.x * v.x + v.y * v.y + v.z * v.z + v.w * v.w;
#pragma unroll
  for (int o = 32; o >= 1; o >>= 1) {
    s += __shfl_xor(s, o);
    ss += __shfl_xor(ss, o);
  }
  __shared__ float ls[2], lss[2];
  if ((t & 63) == 0) { ls[t >> 6] = s; lss[t >> 6] = ss; }
  __syncthreads();
  float S = ls[0] + ls[1];
  float SS = lss[0] + lss[1];
  float mean = S * (1.f / DD);
  float var = SS * (1.f / DD) - mean * mean;
  float rstd = rsqrtf(var + 1e-5f);
  int c = t * 4;
  ushort4 o4;
  o4.x = f2bf((v.x - mean) * rstd * gg[c + 0] + bb[c + 0]);
  o4.y = f2bf((v.y - mean) * rstd * gg[c + 1] + bb[c + 1]);
  o4.z = f2bf((v.z - mean) * rstd * gg[c + 2] + bb[c + 2]);
  o4.w = f2bf((v.w - mean) * rstd * gg[c + 3] + bb[c + 3]);
  ((ushort4*)(dst + (size_t)row * DD))[t] = o4;
}

// ---------------- direct-from-global bf16 GEMM: C(M,N) = A(M,K) * Bt(N,K)^T
// NO LDS, NO barriers. Each wave owns a (FM*16 x FN*16) tile and loads its MFMA
// fragments straight from global (contiguous 16B per lane; L2-cached). 2-deep
// register prefetch pipeline -> fine-grained vmcnt waits, never a full drain.
// EPI 0: QKV (elu+1 for Q/K, pad-mask K/V, V stored transposed per-head)
// EPI 1: fp32 out = acc + bias[col] + residual[row,col]
// EPI 2: bf16 out = gelu(acc + bias[col])
template <int FM, int FN, int K, int EPI>
__global__ __launch_bounds__(256, 2) void gemm_direct(
    const unsigned short* __restrict__ A, const unsigned short* __restrict__ Bt,
    int N,
    const float* __restrict__ e0, const float* __restrict__ e1,
    float* __restrict__ o0, unsigned short* __restrict__ ob,
    unsigned short* __restrict__ okk, unsigned short* __restrict__ ov,
    const unsigned char* __restrict__ msk) {
  const int tid = threadIdx.x;
  const int wid = tid >> 6;
  const int lane = tid & 63;
  const int ln = lane & 15;
  const int quad = lane >> 4;
  // 4 waves arranged 2x2 over a (2*FM*16 x 2*FN*16) block tile
  const int m0 = blockIdx.y * (2 * FM * 16) + (wid >> 1) * (FM * 16);
  const int n0 = blockIdx.x * (2 * FN * 16) + (wid & 1) * (FN * 16);

  const unsigned short* Ap = A + (size_t)(m0 + ln) * K + quad * 8;
  const unsigned short* Bp = Bt + (size_t)(n0 + ln) * K + quad * 8;

  floatx4 acc[FM][FN];
#pragma unroll
  for (int i = 0; i < FM; ++i)
#pragma unroll
    for (int j = 0; j < FN; ++j) acc[i][j] = (floatx4){0.f, 0.f, 0.f, 0.f};

  constexpr int NI = K / 32;
  uint4 ab[2][FM], bb[2][FN];
#pragma unroll
  for (int s = 0; s < 2; ++s) {
#pragma unroll
    for (int i = 0; i < FM; ++i) ab[s][i] = *(const uint4*)(Ap + (size_t)i * 16 * K + s * 32);
#pragma unroll
    for (int j = 0; j < FN; ++j) bb[s][j] = *(const uint4*)(Bp + (size_t)j * 16 * K + s * 32);
  }

#pragma unroll 2
  for (int it = 0; it < NI; ++it) {
    const int s = it & 1;
    bf16x8 af[FM], bf[FN];
#pragma unroll
    for (int i = 0; i < FM; ++i) af[i] = __builtin_bit_cast(bf16x8, ab[s][i]);
#pragma unroll
    for (int j = 0; j < FN; ++j) bf[j] = __builtin_bit_cast(bf16x8, bb[s][j]);
    if (it + 2 < NI) {  // refill this slot for iter it+2 (issues before the MFMAs below)
      const int koff = (it + 2) * 32;
#pragma unroll
      for (int i = 0; i < FM; ++i) ab[s][i] = *(const uint4*)(Ap + (size_t)i * 16 * K + koff);
#pragma unroll
      for (int j = 0; j < FN; ++j) bb[s][j] = *(const uint4*)(Bp + (size_t)j * 16 * K + koff);
    }
#pragma unroll
    for (int i = 0; i < FM; ++i)
#pragma unroll
      for (int j = 0; j < FN; ++j) acc[i][j] = mfma_bf16(af[i], bf[j], acc[i][j]);
  }

#pragma unroll
  for (int mb = 0; mb < FM; ++mb)
#pragma unroll
    for (int nb = 0; nb < FN; ++nb)
#pragma unroll
      for (int r = 0; r < 4; ++r) {
        int row = m0 + mb * 16 + quad * 4 + r;  // C/D: row = quad*4+reg
        int col = n0 + nb * 16 + ln;            //       col = lane&15
        float v = acc[mb][nb][r];
        if constexpr (EPI == 0) {
          int bq = row >> 11, t = row & 2047;
          float padv = msk[(bq << 11) + t] ? 0.f : 1.f;
          if (col < 512) {  // Q = elu(z)+1
            int h = col >> 6, hd = col & 63;
            float q = v > 0.f ? v + 1.f : expf(v);
            ob[(((size_t)(bq * HH + h) * TT + t) << 6) + hd] = f2bf(q);
          } else if (col < 1024) {  // K = (elu(z)+1)*pad
            int c2 = col - 512, h = c2 >> 6, hd = c2 & 63;
            float kf = (v > 0.f ? v + 1.f : expf(v)) * padv;
            okk[(((size_t)(bq * HH + h) * TT + t) << 6) + hd] = f2bf(kf);
          } else {  // V*pad, stored transposed (B,H,HD,T)
            int c2 = col - 1024, h = c2 >> 6, hd = c2 & 63;
            ov[(((size_t)(bq * HH + h) * HD + hd) << 11) + t] = f2bf(v * padv);
          }
        } else if constexpr (EPI == 1) {
          size_t idx = (size_t)row * N + col;
          o0[idx] = v + e0[col] + e1[idx];
        } else {  // EPI == 2: exact gelu
          float z = v + e0[col];
          float g = 0.5f * z * (1.f + erff(z * 0.70710678118654752f));
          ob[(size_t)row * N + col] = f2bf(g);
        }
      }
}

// ---------------- decayed attention, flash-style; i-tile 64, j-tile 128
__global__ __launch_bounds__(256) void attn_kernel(
    const unsigned short* __restrict__ Qg, const unsigned short* __restrict__ Kg,
    const unsigned short* __restrict__ Vtg, const float* __restrict__ dlg,
    unsigned short* __restrict__ attn_out) {
  __shared__ __align__(16) unsigned short Ks[128 * 72];   // K-tile (j,hd), pad 64->72
  __shared__ __align__(16) unsigned short Vts[64 * 136];  // V^T tile (hd,j), pad 128->136
  __shared__ __align__(16) unsigned short Ss[64 * 136];   // S tile (i,j) roundtrip

  const int tid = threadIdx.x;
  const int wid = tid >> 6;
  const int lane = tid & 63;
  const int ln = lane & 15;
  const int quad = lane >> 4;

  const int i0 = blockIdx.x * 64;
  const int bh = blockIdx.y;
  const int b = bh >> 3, h = bh & 7;

  const unsigned short* Qb = Qg + (size_t)bh * TT * HD;
  const unsigned short* Kb = Kg + (size_t)bh * TT * HD;
  const unsigned short* Vb = Vtg + (size_t)bh * HD * TT;

  const float logit = dlg[h];
  const float dec = 1.f / (1.f + expf(-logit));
  const float l2d = log2f(fmaxf(dec, 1e-8f));
  const bool fast = (l2d >= -1.0f);  // factorized path safe (no fp32 overflow) for d>0.5

  // Q A-fragments (rows i0+wid*16+ln), kept in regs across the j-loop
  bf16x8 qa[2];
#pragma unroll
  for (int kb = 0; kb < 2; ++kb)
    qa[kb] = frag16(Qb + (size_t)(i0 + wid * 16 + ln) * HD + kb * 32 + quad * 8);

  // per-lane decay factor tables: d^(i-i0), d^-(i-i0), d^-(j-j0), d^(j-j0)
  float rf[4], rfi[4], cf[8], cfi[8];
#pragma unroll
  for (int r = 0; r < 4; ++r) {
    float il = (float)(wid * 16 + quad * 4 + r);
    rf[r] = exp2f(l2d * il);
    rfi[r] = exp2f(-l2d * il);
  }
#pragma unroll
  for (int nb = 0; nb < 8; ++nb) {
    float jl = (float)(nb * 16 + ln);
    cf[nb] = exp2f(-l2d * jl);
    cfi[nb] = exp2f(l2d * jl);
  }

  floatx4 oacc[4];
#pragma unroll
  for (int i = 0; i < 4; ++i) oacc[i] = (floatx4){0.f, 0.f, 0.f, 0.f};
  float zacc[4] = {0.f, 0.f, 0.f, 0.f};

  for (int j0 = 0; j0 < TT; j0 += 128) {
    const int gap = i0 - j0;
    int mind = 0;
    if (gap >= 128) mind = gap - 127;
    else if (gap <= -64) mind = -gap - 63;
    if (l2d * (float)mind < -40.f) continue;  // max tile weight < 2^-40: negligible

    __syncthreads();  // previous PV reads done before restaging
#pragma unroll
    for (int r2 = 0; r2 < 4; ++r2) {
      int c = tid + r2 * 256;
      int row = c >> 3, c16 = (c & 7) * 8;
      *(uint4*)(&Ks[row * 72 + c16]) = *(const uint4*)(Kb + (size_t)(j0 + row) * HD + c16);
    }
#pragma unroll
    for (int r2 = 0; r2 < 4; ++r2) {
      int c = tid + r2 * 256;
      int row = c >> 4, c16 = (c & 15) * 8;
      *(uint4*)(&Vts[row * 136 + c16]) = *(const uint4*)(Vb + (size_t)row * TT + j0 + c16);
    }
    __syncthreads();

    const float wS = exp2f(l2d * (float)gap);    // d^(i0-j0)   (used when i>=j)
    const float wSb = exp2f(-l2d * (float)gap);  // d^(j0-i0)   (used when j>i)

#pragma unroll
    for (int nb = 0; nb < 8; ++nb) {
      floatx4 sacc = (floatx4){0.f, 0.f, 0.f, 0.f};
#pragma unroll
      for (int kb = 0; kb < 2; ++kb) {
        bf16x8 bk = frag16(&Ks[(nb * 16 + ln) * 72 + kb * 32 + quad * 8]);
        sacc = mfma_bf16(qa[kb], bk, sacc);
      }
#pragma unroll
      for (int r = 0; r < 4; ++r) {
        int il = wid * 16 + quad * 4 + r;
        int jl = nb * 16 + ln;
        int sd = gap + il - jl;  // i - j
        float w;
        if (fast)
          w = (sd >= 0) ? (wS * rf[r]) * cf[nb] : (wSb * rfi[r]) * cfi[nb];
        else
          w = exp2f(l2d * fabsf((float)sd));
        float sv = sacc[r] * w;
        zacc[r] += sv;
        Ss[(size_t)(wid * 16 + quad * 4 + r) * 136 + nb * 16 + ln] = f2bf(sv);
      }
    }
    __syncthreads();  // S visible (also orders within-wave write->read)

    bf16x8 af[4];
#pragma unroll
    for (int kb = 0; kb < 4; ++kb)
      af[kb] = frag16(&Ss[(size_t)(wid * 16 + ln) * 136 + kb * 32 + quad * 8]);
#pragma unroll
    for (int n2 = 0; n2 < 4; ++n2) {
#pragma unroll
      for (int kb = 0; kb < 4; ++kb) {
        bf16x8 bv = frag16(&Vts[(size_t)(n2 * 16 + ln) * 136 + kb * 32 + quad * 8]);
        oacc[n2] = mfma_bf16(af[kb], bv, oacc[n2]);
      }
    }
  }

  // row-sum denominator: reduce zacc across the 16 lanes of each quad
  float rz[4];
#pragma unroll
  for (int r = 0; r < 4; ++r) {
    float z = zacc[r];
    z += __shfl_xor(z, 1);
    z += __shfl_xor(z, 2);
    z += __shfl_xor(z, 4);
    z += __shfl_xor(z, 8);
    rz[r] = 1.f / fmaxf(z, 1e-6f);
  }

#pragma unroll
  for (int n2 = 0; n2 < 4; ++n2)
#pragma unroll
    for (int r = 0; r < 4; ++r) {
      int i = i0 + wid * 16 + quad * 4 + r;
      int col = h * 64 + n2 * 16 + ln;
      attn_out[(size_t)(b * TT + i) * DD + col] = f2bf(oacc[n2][r] * rz[r]);
    }
}

extern "C" void kernel_launch(void* const* d_in, const int* in_sizes, int n_in,
                              void* d_out, int out_size, void* d_ws, size_t ws_size,
                              hipStream_t stream) {
  const float* x = (const float*)d_in[0];
  const unsigned char* msk = (const unsigned char*)d_in[1];
  const float* wq = (const float*)d_in[2];
  const float* wk = (const float*)d_in[3];
  const float* wv = (const float*)d_in[4];
  const float* wo = (const float*)d_in[5];
  const float* bo = (const float*)d_in[6];
  const float* g1 = (const float*)d_in[7];
  const float* b1 = (const float*)d_in[8];
  const float* g2 = (const float*)d_in[9];
  const float* b2 = (const float*)d_in[10];
  const float* w1 = (const float*)d_in[11];
  const float* bf1 = (const float*)d_in[12];
  const float* w2 = (const float*)d_in[13];
  const float* bf2 = (const float*)d_in[14];
  const float* dlg = (const float*)d_in[15];
  float* out = (float*)d_out;

  char* p = (char*)d_ws;
  size_t off = 0;
  auto carve = [&](size_t bytes) {
    char* q = p + off;
    off += (bytes + 255) & ~(size_t)255;
    return q;
  };
  unsigned short* xn = (unsigned short*)carve((size_t)M4 * DD * 2);
  unsigned short* wqkvT = (unsigned short*)carve((size_t)1536 * DD * 2);
  unsigned short* woT = (unsigned short*)carve((size_t)DD * DD * 2);
  unsigned short* w1T = (unsigned short*)carve((size_t)FF_ * DD * 2);
  unsigned short* w2T = (unsigned short*)carve((size_t)DD * FF_ * 2);
  unsigned short* Qb = (unsigned short*)carve((size_t)16 * TT * HD * 2);
  unsigned short* Kb = (unsigned short*)carve((size_t)16 * TT * HD * 2);
  unsigned short* Vtb = (unsigned short*)carve((size_t)16 * HD * TT * 2);
  unsigned short* attn = (unsigned short*)carve((size_t)M4 * DD * 2);
  float* x2 = (float*)carve((size_t)M4 * DD * 4);
  unsigned short* xn2 = (unsigned short*)carve((size_t)M4 * DD * 2);
  unsigned short* ffh = (unsigned short*)carve((size_t)M4 * FF_ * 2);

  transpose_all<<<3072, dim3(32, 8), 0, stream>>>(wq, wk, wv, wo, w1, w2,
                                                  wqkvT, woT, w1T, w2T);

  ln_kernel<<<M4, 128, 0, stream>>>(x, g1, b1, xn);

  // QKV: M=4096, N=1536, K=512 — 128x128 block tiles, 384 blocks, no LDS
  gemm_direct<4, 4, 512, 0><<<dim3(1536 / 128, M4 / 128), 256, 0, stream>>>(
      xn, wqkvT, 1536, nullptr, nullptr, nullptr, Qb, Kb, Vtb, msk);

  attn_kernel<<<dim3(TT / 64, 16), 256, 0, stream>>>(Qb, Kb, Vtb, dlg, attn);

  // out-proj: M=4096, N=512, K=512
  gemm_direct<4, 4, 512, 1><<<dim3(DD / 128, M4 / 128), 256, 0, stream>>>(
      attn, woT, DD, bo, x, x2, nullptr, nullptr, nullptr, nullptr);

  ln_kernel<<<M4, 128, 0, stream>>>(x2, g2, b2, xn2);

  // FFN1: M=4096, N=2048, K=512
  gemm_direct<4, 4, 512, 2><<<dim3(FF_ / 128, M4 / 128), 256, 0, stream>>>(
      xn2, w1T, FF_, bf1, nullptr, nullptr, ffh, nullptr, nullptr, nullptr);

  // FFN2: M=4096, N=512, K=2048
  gemm_direct<4, 4, 2048, 1><<<dim3(DD / 128, M4 / 128), 256, 0, stream>>>(
      ffh, w2T, DD, bf2, x2, out, nullptr, nullptr, nullptr, nullptr);
}

// Round 4
// 218.643 us; speedup vs baseline: 1.3231x; 1.3231x over previous
//
#include <hip/hip_runtime.h>
#include <hip/hip_bf16.h>
#include <math.h>

// Shapes (fixed by the problem)
#define BB 2
#define TT 2048
#define DD 512
#define HH 8
#define HD 64
#define FF_ 2048
#define M4 4096  // BB*TT

typedef __attribute__((ext_vector_type(8))) __bf16 bf16x8;
typedef __attribute__((ext_vector_type(4))) float floatx4;

__device__ __forceinline__ unsigned short f2bf(float f) {
  unsigned u = __builtin_bit_cast(unsigned, f);
  u += 0x7fffu + ((u >> 16) & 1u);  // RNE
  return (unsigned short)(u >> 16);
}

__device__ __forceinline__ bf16x8 frag16(const unsigned short* p) {
  return __builtin_bit_cast(bf16x8, *(const uint4*)p);
}

__device__ __forceinline__ floatx4 mfma_bf16(bf16x8 a, bf16x8 b, floatx4 c) {
  return __builtin_amdgcn_mfma_f32_16x16x32_bf16(a, b, c, 0, 0, 0);
}

// async global->LDS, 16B per lane; LDS dest = wave-uniform base + lane*16
__device__ __forceinline__ void gl_lds16(const unsigned short* g, unsigned short* l) {
  __builtin_amdgcn_global_load_lds(
      (const __attribute__((address_space(1))) unsigned int*)g,
      (__attribute__((address_space(3))) unsigned int*)l, 16, 0, 0);
}

// ---------------- all 6 weight transposes in ONE launch: src (K,N) f32 -> dst (N,K) bf16
__global__ void transpose_all(const float* __restrict__ wq, const float* __restrict__ wk,
                              const float* __restrict__ wv, const float* __restrict__ wo,
                              const float* __restrict__ w1, const float* __restrict__ w2,
                              unsigned short* __restrict__ wqkvT, unsigned short* __restrict__ woT,
                              unsigned short* __restrict__ w1T, unsigned short* __restrict__ w2T) {
  __shared__ float tile[32][33];
  const int bid = blockIdx.x;
  const float* src;
  unsigned short* dst;
  int Kd = 512, Nd = 512, tIdx;
  if (bid < 256) { src = wq; dst = wqkvT; tIdx = bid; }
  else if (bid < 512) { src = wk; dst = wqkvT + 512 * 512; tIdx = bid - 256; }
  else if (bid < 768) { src = wv; dst = wqkvT + 2 * 512 * 512; tIdx = bid - 512; }
  else if (bid < 1024) { src = wo; dst = woT; tIdx = bid - 768; }
  else if (bid < 2048) { src = w1; dst = w1T; Nd = 2048; tIdx = bid - 1024; }
  else { src = w2; dst = w2T; Kd = 2048; tIdx = bid - 2048; }
  const int nTilesX = Nd / 32;
  const int n0 = (tIdx % nTilesX) * 32, k0 = (tIdx / nTilesX) * 32;
  for (int i = threadIdx.y; i < 32; i += 8)
    tile[i][threadIdx.x] = src[(size_t)(k0 + i) * Nd + n0 + threadIdx.x];
  __syncthreads();
  for (int i = threadIdx.y; i < 32; i += 8)
    dst[(size_t)(n0 + i) * Kd + k0 + threadIdx.x] = f2bf(tile[threadIdx.x][i]);
}

// ---------------- LayerNorm: fp32 (rows of 512) -> bf16
__global__ __launch_bounds__(128) void ln_kernel(const float* __restrict__ src,
                                                 const float* __restrict__ gg,
                                                 const float* __restrict__ bb,
                                                 unsigned short* __restrict__ dst) {
  const int row = blockIdx.x;
  const int t = threadIdx.x;
  float4 v = ((const float4*)(src + (size_t)row * DD))[t];
  float s = v.x + v.y + v.z + v.w;
  float ss = v.x * v.x + v.y * v.y + v.z * v.z + v.w * v.w;
#pragma unroll
  for (int o = 32; o >= 1; o >>= 1) {
    s += __shfl_xor(s, o);
    ss += __shfl_xor(ss, o);
  }
  __shared__ float ls[2], lss[2];
  if ((t & 63) == 0) { ls[t >> 6] = s; lss[t >> 6] = ss; }
  __syncthreads();
  float S = ls[0] + ls[1];
  float SS = lss[0] + lss[1];
  float mean = S * (1.f / DD);
  float var = SS * (1.f / DD) - mean * mean;
  float rstd = rsqrtf(var + 1e-5f);
  int c = t * 4;
  ushort4 o4;
  o4.x = f2bf((v.x - mean) * rstd * gg[c + 0] + bb[c + 0]);
  o4.y = f2bf((v.y - mean) * rstd * gg[c + 1] + bb[c + 1]);
  o4.z = f2bf((v.z - mean) * rstd * gg[c + 2] + bb[c + 2]);
  o4.w = f2bf((v.w - mean) * rstd * gg[c + 3] + bb[c + 3]);
  ((ushort4*)(dst + (size_t)row * DD))[t] = o4;
}

// ---------------- m97-pattern bf16 GEMM: C(M,N) = A(M,K) * Bt(N,K)^T
// global_load_lds(16B) staging, unpadded 64B-row LDS, 2-barrier K-loop.
// Grid TRANSPOSED: blockIdx.x = m-tile, blockIdx.y = n-tile -> XCD = x%8
// row-bands A across XCD L2s (A fetched ~once; B replicated 8x, B is small).
// EPI 0: QKV (elu+1 for Q/K, pad-mask K/V, V stored transposed per-head)
// EPI 1: fp32 out = acc + bias[col] + residual[row,col]
// EPI 2: bf16 out = gelu(acc + bias[col])
template <int BM, int BN, int K, int EPI>
__global__ __launch_bounds__(256, 4) void gemm_m97(
    const unsigned short* __restrict__ A, const unsigned short* __restrict__ Bt,
    int N,
    const float* __restrict__ e0, const float* __restrict__ e1,
    float* __restrict__ o0, unsigned short* __restrict__ ob,
    unsigned short* __restrict__ okk, unsigned short* __restrict__ ov,
    const unsigned char* __restrict__ msk) {
  constexpr int FM = BM / 32;
  constexpr int FN = BN / 32;
  constexpr int NT = (BM + BN) / 16;  // 16-row staging instrs per K-step
  __shared__ __align__(16) unsigned short S[(BM + BN) * 32];  // A rows then B rows, 32 shorts (64B) each

  const int tid = threadIdx.x;
  const int wid = tid >> 6;
  const int lane = tid & 63;
  const int ln = lane & 15;
  const int quad = lane >> 4;
  const int wm = (wid >> 1) * (BM / 2);
  const int wn = (wid & 1) * (BN / 2);
  const int m0 = blockIdx.x * BM;  // x = m-tile (XCD row-banding)
  const int n0 = blockIdx.y * BN;
  const int lrow = lane >> 2;       // 0..15: row within 16-row chunk
  const int lk = (lane & 3) * 8;    // shorts: 16B slice within the 64B row

  floatx4 acc[FM][FN];
#pragma unroll
  for (int i = 0; i < FM; ++i)
#pragma unroll
    for (int j = 0; j < FN; ++j) acc[i][j] = (floatx4){0.f, 0.f, 0.f, 0.f};

  for (int k0 = 0; k0 < K; k0 += 32) {
    for (int i = wid; i < NT; i += 4) {
      int r = i * 16 + lrow;
      const unsigned short* g = (r < BM)
          ? A + (size_t)(m0 + r) * K + k0 + lk
          : Bt + (size_t)(n0 + (r - BM)) * K + k0 + lk;
      gl_lds16(g, &S[i * 16 * 32]);  // lane l -> base + l*16B == row (base+l/4), slice (l&3)
    }
    __syncthreads();  // drains vmcnt(0): staged tile visible

    bf16x8 af[FM], bf[FN];
#pragma unroll
    for (int mb = 0; mb < FM; ++mb)
      af[mb] = frag16(&S[(wm + mb * 16 + ln) * 32 + quad * 8]);
#pragma unroll
    for (int nb = 0; nb < FN; ++nb)
      bf[nb] = frag16(&S[(BM + wn + nb * 16 + ln) * 32 + quad * 8]);
#pragma unroll
    for (int mb = 0; mb < FM; ++mb)
#pragma unroll
      for (int nb = 0; nb < FN; ++nb)
        acc[mb][nb] = mfma_bf16(af[mb], bf[nb], acc[mb][nb]);
    __syncthreads();  // frag reads done before next restage
  }

#pragma unroll
  for (int mb = 0; mb < FM; ++mb)
#pragma unroll
    for (int nb = 0; nb < FN; ++nb)
#pragma unroll
      for (int r = 0; r < 4; ++r) {
        int row = m0 + wm + mb * 16 + quad * 4 + r;  // C/D: row = quad*4+reg
        int col = n0 + wn + nb * 16 + ln;            //       col = lane&15
        float v = acc[mb][nb][r];
        if constexpr (EPI == 0) {
          int bq = row >> 11, t = row & 2047;
          float padv = msk[(bq << 11) + t] ? 0.f : 1.f;
          if (col < 512) {  // Q = elu(z)+1
            int h = col >> 6, hd = col & 63;
            float q = v > 0.f ? v + 1.f : expf(v);
            ob[(((size_t)(bq * HH + h) * TT + t) << 6) + hd] = f2bf(q);
          } else if (col < 1024) {  // K = (elu(z)+1)*pad
            int c2 = col - 512, h = c2 >> 6, hd = c2 & 63;
            float kf = (v > 0.f ? v + 1.f : expf(v)) * padv;
            okk[(((size_t)(bq * HH + h) * TT + t) << 6) + hd] = f2bf(kf);
          } else {  // V*pad, stored transposed (B,H,HD,T)
            int c2 = col - 1024, h = c2 >> 6, hd = c2 & 63;
            ov[(((size_t)(bq * HH + h) * HD + hd) << 11) + t] = f2bf(v * padv);
          }
        } else if constexpr (EPI == 1) {
          size_t idx = (size_t)row * N + col;
          o0[idx] = v + e0[col] + e1[idx];
        } else {  // EPI == 2: exact gelu
          float z = v + e0[col];
          float g = 0.5f * z * (1.f + erff(z * 0.70710678118654752f));
          ob[(size_t)row * N + col] = f2bf(g);
        }
      }
}

// ---------------- decayed attention, flash-style; i-tile 64, j-tile 128
__global__ __launch_bounds__(256) void attn_kernel(
    const unsigned short* __restrict__ Qg, const unsigned short* __restrict__ Kg,
    const unsigned short* __restrict__ Vtg, const float* __restrict__ dlg,
    unsigned short* __restrict__ attn_out) {
  __shared__ __align__(16) unsigned short Ks[128 * 72];   // K-tile (j,hd), pad 64->72
  __shared__ __align__(16) unsigned short Vts[64 * 136];  // V^T tile (hd,j), pad 128->136
  __shared__ __align__(16) unsigned short Ss[64 * 136];   // S tile (i,j) roundtrip

  const int tid = threadIdx.x;
  const int wid = tid >> 6;
  const int lane = tid & 63;
  const int ln = lane & 15;
  const int quad = lane >> 4;

  const int i0 = blockIdx.x * 64;
  const int bh = blockIdx.y;
  const int b = bh >> 3, h = bh & 7;

  const unsigned short* Qb = Qg + (size_t)bh * TT * HD;
  const unsigned short* Kb = Kg + (size_t)bh * TT * HD;
  const unsigned short* Vb = Vtg + (size_t)bh * HD * TT;

  const float logit = dlg[h];
  const float dec = 1.f / (1.f + expf(-logit));
  const float l2d = log2f(fmaxf(dec, 1e-8f));
  const bool fast = (l2d >= -1.0f);  // factorized path safe (no fp32 overflow) for d>0.5

  // Q A-fragments (rows i0+wid*16+ln), kept in regs across the j-loop
  bf16x8 qa[2];
#pragma unroll
  for (int kb = 0; kb < 2; ++kb)
    qa[kb] = frag16(Qb + (size_t)(i0 + wid * 16 + ln) * HD + kb * 32 + quad * 8);

  // per-lane decay factor tables: d^(i-i0), d^-(i-i0), d^-(j-j0), d^(j-j0)
  float rf[4], rfi[4], cf[8], cfi[8];
#pragma unroll
  for (int r = 0; r < 4; ++r) {
    float il = (float)(wid * 16 + quad * 4 + r);
    rf[r] = exp2f(l2d * il);
    rfi[r] = exp2f(-l2d * il);
  }
#pragma unroll
  for (int nb = 0; nb < 8; ++nb) {
    float jl = (float)(nb * 16 + ln);
    cf[nb] = exp2f(-l2d * jl);
    cfi[nb] = exp2f(l2d * jl);
  }

  floatx4 oacc[4];
#pragma unroll
  for (int i = 0; i < 4; ++i) oacc[i] = (floatx4){0.f, 0.f, 0.f, 0.f};
  float zacc[4] = {0.f, 0.f, 0.f, 0.f};

  for (int j0 = 0; j0 < TT; j0 += 128) {
    const int gap = i0 - j0;
    int mind = 0;
    if (gap >= 128) mind = gap - 127;
    else if (gap <= -64) mind = -gap - 63;
    if (l2d * (float)mind < -40.f) continue;  // max tile weight < 2^-40: negligible

    __syncthreads();  // previous PV reads done before restaging
#pragma unroll
    for (int r2 = 0; r2 < 4; ++r2) {
      int c = tid + r2 * 256;
      int row = c >> 3, c16 = (c & 7) * 8;
      *(uint4*)(&Ks[row * 72 + c16]) = *(const uint4*)(Kb + (size_t)(j0 + row) * HD + c16);
    }
#pragma unroll
    for (int r2 = 0; r2 < 4; ++r2) {
      int c = tid + r2 * 256;
      int row = c >> 4, c16 = (c & 15) * 8;
      *(uint4*)(&Vts[row * 136 + c16]) = *(const uint4*)(Vb + (size_t)row * TT + j0 + c16);
    }
    __syncthreads();

    const float wS = exp2f(l2d * (float)gap);    // d^(i0-j0)   (used when i>=j)
    const float wSb = exp2f(-l2d * (float)gap);  // d^(j0-i0)   (used when j>i)

#pragma unroll
    for (int nb = 0; nb < 8; ++nb) {
      floatx4 sacc = (floatx4){0.f, 0.f, 0.f, 0.f};
#pragma unroll
      for (int kb = 0; kb < 2; ++kb) {
        bf16x8 bk = frag16(&Ks[(nb * 16 + ln) * 72 + kb * 32 + quad * 8]);
        sacc = mfma_bf16(qa[kb], bk, sacc);
      }
#pragma unroll
      for (int r = 0; r < 4; ++r) {
        int il = wid * 16 + quad * 4 + r;
        int jl = nb * 16 + ln;
        int sd = gap + il - jl;  // i - j
        float w;
        if (fast)
          w = (sd >= 0) ? (wS * rf[r]) * cf[nb] : (wSb * rfi[r]) * cfi[nb];
        else
          w = exp2f(l2d * fabsf((float)sd));
        float sv = sacc[r] * w;
        zacc[r] += sv;
        Ss[(size_t)(wid * 16 + quad * 4 + r) * 136 + nb * 16 + ln] = f2bf(sv);
      }
    }
    __syncthreads();  // S visible (also orders within-wave write->read)

    bf16x8 af[4];
#pragma unroll
    for (int kb = 0; kb < 4; ++kb)
      af[kb] = frag16(&Ss[(size_t)(wid * 16 + ln) * 136 + kb * 32 + quad * 8]);
#pragma unroll
    for (int n2 = 0; n2 < 4; ++n2) {
#pragma unroll
      for (int kb = 0; kb < 4; ++kb) {
        bf16x8 bv = frag16(&Vts[(size_t)(n2 * 16 + ln) * 136 + kb * 32 + quad * 8]);
        oacc[n2] = mfma_bf16(af[kb], bv, oacc[n2]);
      }
    }
  }

  // row-sum denominator: reduce zacc across the 16 lanes of each quad
  float rz[4];
#pragma unroll
  for (int r = 0; r < 4; ++r) {
    float z = zacc[r];
    z += __shfl_xor(z, 1);
    z += __shfl_xor(z, 2);
    z += __shfl_xor(z, 4);
    z += __shfl_xor(z, 8);
    rz[r] = 1.f / fmaxf(z, 1e-6f);
  }

#pragma unroll
  for (int n2 = 0; n2 < 4; ++n2)
#pragma unroll
    for (int r = 0; r < 4; ++r) {
      int i = i0 + wid * 16 + quad * 4 + r;
      int col = h * 64 + n2 * 16 + ln;
      attn_out[(size_t)(b * TT + i) * DD + col] = f2bf(oacc[n2][r] * rz[r]);
    }
}

extern "C" void kernel_launch(void* const* d_in, const int* in_sizes, int n_in,
                              void* d_out, int out_size, void* d_ws, size_t ws_size,
                              hipStream_t stream) {
  const float* x = (const float*)d_in[0];
  const unsigned char* msk = (const unsigned char*)d_in[1];
  const float* wq = (const float*)d_in[2];
  const float* wk = (const float*)d_in[3];
  const float* wv = (const float*)d_in[4];
  const float* wo = (const float*)d_in[5];
  const float* bo = (const float*)d_in[6];
  const float* g1 = (const float*)d_in[7];
  const float* b1 = (const float*)d_in[8];
  const float* g2 = (const float*)d_in[9];
  const float* b2 = (const float*)d_in[10];
  const float* w1 = (const float*)d_in[11];
  const float* bf1 = (const float*)d_in[12];
  const float* w2 = (const float*)d_in[13];
  const float* bf2 = (const float*)d_in[14];
  const float* dlg = (const float*)d_in[15];
  float* out = (float*)d_out;

  char* p = (char*)d_ws;
  size_t off = 0;
  auto carve = [&](size_t bytes) {
    char* q = p + off;
    off += (bytes + 255) & ~(size_t)255;
    return q;
  };
  unsigned short* xn = (unsigned short*)carve((size_t)M4 * DD * 2);
  unsigned short* wqkvT = (unsigned short*)carve((size_t)1536 * DD * 2);
  unsigned short* woT = (unsigned short*)carve((size_t)DD * DD * 2);
  unsigned short* w1T = (unsigned short*)carve((size_t)FF_ * DD * 2);
  unsigned short* w2T = (unsigned short*)carve((size_t)DD * FF_ * 2);
  unsigned short* Qb = (unsigned short*)carve((size_t)16 * TT * HD * 2);
  unsigned short* Kb = (unsigned short*)carve((size_t)16 * TT * HD * 2);
  unsigned short* Vtb = (unsigned short*)carve((size_t)16 * HD * TT * 2);
  unsigned short* attn = (unsigned short*)carve((size_t)M4 * DD * 2);
  float* x2 = (float*)carve((size_t)M4 * DD * 4);
  unsigned short* xn2 = (unsigned short*)carve((size_t)M4 * DD * 2);
  unsigned short* ffh = (unsigned short*)carve((size_t)M4 * FF_ * 2);

  transpose_all<<<3072, dim3(32, 8), 0, stream>>>(wq, wk, wv, wo, w1, w2,
                                                  wqkvT, woT, w1T, w2T);

  ln_kernel<<<M4, 128, 0, stream>>>(x, g1, b1, xn);

  // QKV: M=4096, N=1536, K=512 — 64x128 tiles, grid (64 m-tiles, 12 n-tiles) = 768 blocks (3/CU)
  gemm_m97<64, 128, 512, 0><<<dim3(M4 / 64, 1536 / 128), 256, 0, stream>>>(
      xn, wqkvT, 1536, nullptr, nullptr, nullptr, Qb, Kb, Vtb, msk);

  attn_kernel<<<dim3(TT / 64, 16), 256, 0, stream>>>(Qb, Kb, Vtb, dlg, attn);

  // out-proj: M=4096, N=512, K=512 — 32x64 tiles, grid (128, 8) = 1024 blocks (4/CU)
  gemm_m97<32, 64, 512, 1><<<dim3(M4 / 32, DD / 64), 256, 0, stream>>>(
      attn, woT, DD, bo, x, x2, nullptr, nullptr, nullptr, nullptr);

  ln_kernel<<<M4, 128, 0, stream>>>(x2, g2, b2, xn2);

  // FFN1: M=4096, N=2048, K=512 — 64x128 tiles, grid (64, 16) = 1024 blocks (4/CU)
  gemm_m97<64, 128, 512, 2><<<dim3(M4 / 64, FF_ / 128), 256, 0, stream>>>(
      xn2, w1T, FF_, bf1, nullptr, nullptr, ffh, nullptr, nullptr, nullptr);

  // FFN2: M=4096, N=512, K=2048 — 32x64 tiles, grid (128, 8) = 1024 blocks (4/CU)
  gemm_m97<32, 64, 2048, 1><<<dim3(M4 / 32, DD / 64), 256, 0, stream>>>(
      ffh, w2T, DD, bf2, x2, out, nullptr, nullptr, nullptr, nullptr);
}

// Round 5
// 201.002 us; speedup vs baseline: 1.4392x; 1.0878x over previous
//
#include <hip/hip_runtime.h>
#include <hip/hip_bf16.h>
#include <math.h>

// Shapes (fixed by the problem)
#define BB 2
#define TT 2048
#define DD 512
#define HH 8
#define HD 64
#define FF_ 2048
#define M4 4096  // BB*TT

typedef __attribute__((ext_vector_type(8))) __bf16 bf16x8;
typedef __attribute__((ext_vector_type(4))) float floatx4;

__device__ __forceinline__ unsigned short f2bf(float f) {
  unsigned u = __builtin_bit_cast(unsigned, f);
  u += 0x7fffu + ((u >> 16) & 1u);  // RNE
  return (unsigned short)(u >> 16);
}

__device__ __forceinline__ bf16x8 frag16(const unsigned short* p) {
  return __builtin_bit_cast(bf16x8, *(const uint4*)p);
}

__device__ __forceinline__ floatx4 mfma_bf16(bf16x8 a, bf16x8 b, floatx4 c) {
  return __builtin_amdgcn_mfma_f32_16x16x32_bf16(a, b, c, 0, 0, 0);
}

// async global->LDS, 16B per lane; LDS dest = wave-uniform base + lane*16
__device__ __forceinline__ void gl_lds16(const unsigned short* g, unsigned short* l) {
  __builtin_amdgcn_global_load_lds(
      (const __attribute__((address_space(1))) unsigned int*)g,
      (__attribute__((address_space(3))) unsigned int*)l, 16, 0, 0);
}

// ---------------- prep: 6 weight transposes (blocks 0..3071) + LayerNorm1 (blocks 3072..5119)
// transpose: src (K,N) f32 -> dst (N,K) bf16.  ln: 2 rows per block, 128 thr/row.
__global__ __launch_bounds__(256) void prep_kernel(
    const float* __restrict__ wq, const float* __restrict__ wk,
    const float* __restrict__ wv, const float* __restrict__ wo,
    const float* __restrict__ w1, const float* __restrict__ w2,
    unsigned short* __restrict__ wqkvT, unsigned short* __restrict__ woT,
    unsigned short* __restrict__ w1T, unsigned short* __restrict__ w2T,
    const float* __restrict__ x, const float* __restrict__ g1,
    const float* __restrict__ b1, unsigned short* __restrict__ xn) {
  __shared__ float tile[32][33];
  __shared__ float ls[4], lss[4];
  const int bid = blockIdx.x;
  const int tid = threadIdx.x;
  if (bid < 3072) {
    const int tx = tid & 31, ty = tid >> 5;
    const float* src;
    unsigned short* dst;
    int Kd = 512, Nd = 512, tIdx;
    if (bid < 256) { src = wq; dst = wqkvT; tIdx = bid; }
    else if (bid < 512) { src = wk; dst = wqkvT + 512 * 512; tIdx = bid - 256; }
    else if (bid < 768) { src = wv; dst = wqkvT + 2 * 512 * 512; tIdx = bid - 512; }
    else if (bid < 1024) { src = wo; dst = woT; tIdx = bid - 768; }
    else if (bid < 2048) { src = w1; dst = w1T; Nd = 2048; tIdx = bid - 1024; }
    else { src = w2; dst = w2T; Kd = 2048; tIdx = bid - 2048; }
    const int nTilesX = Nd / 32;
    const int n0 = (tIdx % nTilesX) * 32, k0 = (tIdx / nTilesX) * 32;
    for (int i = ty; i < 32; i += 8)
      tile[i][tx] = src[(size_t)(k0 + i) * Nd + n0 + tx];
    __syncthreads();
    for (int i = ty; i < 32; i += 8)
      dst[(size_t)(n0 + i) * Kd + k0 + tx] = f2bf(tile[tx][i]);
  } else {
    const int row = (bid - 3072) * 2 + (tid >> 7);
    const int t = tid & 127;
    float4 v = ((const float4*)(x + (size_t)row * DD))[t];
    float s = v.x + v.y + v.z + v.w;
    float ss = v.x * v.x + v.y * v.y + v.z * v.z + v.w * v.w;
#pragma unroll
    for (int o = 32; o >= 1; o >>= 1) {
      s += __shfl_xor(s, o);
      ss += __shfl_xor(ss, o);
    }
    if ((tid & 63) == 0) { ls[tid >> 6] = s; lss[tid >> 6] = ss; }
    __syncthreads();
    const int wb = (tid >> 7) * 2;
    float S = ls[wb] + ls[wb + 1];
    float SS = lss[wb] + lss[wb + 1];
    float mean = S * (1.f / DD);
    float var = SS * (1.f / DD) - mean * mean;
    float rstd = rsqrtf(var + 1e-5f);
    int c = t * 4;
    ushort4 o4;
    o4.x = f2bf((v.x - mean) * rstd * g1[c + 0] + b1[c + 0]);
    o4.y = f2bf((v.y - mean) * rstd * g1[c + 1] + b1[c + 1]);
    o4.z = f2bf((v.z - mean) * rstd * g1[c + 2] + b1[c + 2]);
    o4.w = f2bf((v.w - mean) * rstd * g1[c + 3] + b1[c + 3]);
    ((ushort4*)(xn + (size_t)row * DD))[t] = o4;
  }
}

// ---------------- LayerNorm (standalone, for ln2): fp32 (rows of 512) -> bf16
__global__ __launch_bounds__(128) void ln_kernel(const float* __restrict__ src,
                                                 const float* __restrict__ gg,
                                                 const float* __restrict__ bb,
                                                 unsigned short* __restrict__ dst) {
  const int row = blockIdx.x;
  const int t = threadIdx.x;
  float4 v = ((const float4*)(src + (size_t)row * DD))[t];
  float s = v.x + v.y + v.z + v.w;
  float ss = v.x * v.x + v.y * v.y + v.z * v.z + v.w * v.w;
#pragma unroll
  for (int o = 32; o >= 1; o >>= 1) {
    s += __shfl_xor(s, o);
    ss += __shfl_xor(ss, o);
  }
  __shared__ float ls[2], lss[2];
  if ((t & 63) == 0) { ls[t >> 6] = s; lss[t >> 6] = ss; }
  __syncthreads();
  float S = ls[0] + ls[1];
  float SS = lss[0] + lss[1];
  float mean = S * (1.f / DD);
  float var = SS * (1.f / DD) - mean * mean;
  float rstd = rsqrtf(var + 1e-5f);
  int c = t * 4;
  ushort4 o4;
  o4.x = f2bf((v.x - mean) * rstd * gg[c + 0] + bb[c + 0]);
  o4.y = f2bf((v.y - mean) * rstd * gg[c + 1] + bb[c + 1]);
  o4.z = f2bf((v.z - mean) * rstd * gg[c + 2] + bb[c + 2]);
  o4.w = f2bf((v.w - mean) * rstd * gg[c + 3] + bb[c + 3]);
  ((ushort4*)(dst + (size_t)row * DD))[t] = o4;
}

// ---------------- K-panel bf16 GEMM: C(M,N) = A(M,K) * Bt(N,K)^T
// KU panels of 32 K-elements staged per barrier pair (global_load_lds 16B,
// m97-validated 64B-row LDS layout per panel). KU x the MFMA work and KU x the
// bytes in flight per barrier drain vs the plain m97 loop.
// Grid transposed: blockIdx.x = m-tile (XCD row-banding of A).
// EPI 0: QKV (elu+1 for Q/K, pad-mask K/V, V stored transposed per-head)
// EPI 1: fp32 out = acc + bias[col] + residual[row,col]
// EPI 2: bf16 out = gelu(acc + bias[col])
template <int BM, int BN, int KU, int K, int EPI>
__global__ __launch_bounds__(256, 4) void gemm_ku(
    const unsigned short* __restrict__ A, const unsigned short* __restrict__ Bt,
    int N,
    const float* __restrict__ e0, const float* __restrict__ e1,
    float* __restrict__ o0, unsigned short* __restrict__ ob,
    unsigned short* __restrict__ okk, unsigned short* __restrict__ ov,
    const unsigned char* __restrict__ msk) {
  constexpr int FM = BM / 32;
  constexpr int FN = BN / 32;
  constexpr int PAN = BM + BN;   // rows per panel (A rows then B rows)
  constexpr int NT = PAN / 16;   // gl_lds16 instrs per panel
  __shared__ __align__(16) unsigned short S[KU][PAN * 32];

  const int tid = threadIdx.x;
  const int wid = tid >> 6;
  const int lane = tid & 63;
  const int ln = lane & 15;
  const int quad = lane >> 4;
  const int wm = (wid >> 1) * (BM / 2);
  const int wn = (wid & 1) * (BN / 2);
  const int m0 = blockIdx.x * BM;  // x = m-tile (XCD row-banding)
  const int n0 = blockIdx.y * BN;
  const int lrow = lane >> 2;      // row within a 16-row staging chunk
  const int lk = (lane & 3) * 8;   // 16B slice within the 64B panel row

  floatx4 acc[FM][FN];
#pragma unroll
  for (int i = 0; i < FM; ++i)
#pragma unroll
    for (int j = 0; j < FN; ++j) acc[i][j] = (floatx4){0.f, 0.f, 0.f, 0.f};

  for (int k0 = 0; k0 < K; k0 += KU * 32) {
#pragma unroll
    for (int p = 0; p < KU; ++p)
      for (int i = wid; i < NT; i += 4) {
        int r = i * 16 + lrow;
        const unsigned short* g = (r < BM)
            ? A + (size_t)(m0 + r) * K + k0 + p * 32 + lk
            : Bt + (size_t)(n0 + (r - BM)) * K + k0 + p * 32 + lk;
        gl_lds16(g, &S[p][i * 512]);  // 16 rows x 64B per instr
      }
    __syncthreads();  // drains vmcnt(0): all KU panels visible

#pragma unroll
    for (int p = 0; p < KU; ++p) {
      bf16x8 af[FM], bf[FN];
#pragma unroll
      for (int mb = 0; mb < FM; ++mb)
        af[mb] = frag16(&S[p][(wm + mb * 16 + ln) * 32 + quad * 8]);
#pragma unroll
      for (int nb = 0; nb < FN; ++nb)
        bf[nb] = frag16(&S[p][(BM + wn + nb * 16 + ln) * 32 + quad * 8]);
#pragma unroll
      for (int mb = 0; mb < FM; ++mb)
#pragma unroll
        for (int nb = 0; nb < FN; ++nb)
          acc[mb][nb] = mfma_bf16(af[mb], bf[nb], acc[mb][nb]);
    }
    __syncthreads();  // frag reads done before next restage
  }

#pragma unroll
  for (int mb = 0; mb < FM; ++mb)
#pragma unroll
    for (int nb = 0; nb < FN; ++nb)
#pragma unroll
      for (int r = 0; r < 4; ++r) {
        int row = m0 + wm + mb * 16 + quad * 4 + r;  // C/D: row = quad*4+reg
        int col = n0 + wn + nb * 16 + ln;            //       col = lane&15
        float v = acc[mb][nb][r];
        if constexpr (EPI == 0) {
          int bq = row >> 11, t = row & 2047;
          float padv = msk[(bq << 11) + t] ? 0.f : 1.f;
          if (col < 512) {  // Q = elu(z)+1
            int h = col >> 6, hd = col & 63;
            float q = v > 0.f ? v + 1.f : expf(v);
            ob[(((size_t)(bq * HH + h) * TT + t) << 6) + hd] = f2bf(q);
          } else if (col < 1024) {  // K = (elu(z)+1)*pad
            int c2 = col - 512, h = c2 >> 6, hd = c2 & 63;
            float kf = (v > 0.f ? v + 1.f : expf(v)) * padv;
            okk[(((size_t)(bq * HH + h) * TT + t) << 6) + hd] = f2bf(kf);
          } else {  // V*pad, stored transposed (B,H,HD,T)
            int c2 = col - 1024, h = c2 >> 6, hd = c2 & 63;
            ov[(((size_t)(bq * HH + h) * HD + hd) << 11) + t] = f2bf(v * padv);
          }
        } else if constexpr (EPI == 1) {
          size_t idx = (size_t)row * N + col;
          o0[idx] = v + e0[col] + e1[idx];
        } else {  // EPI == 2: exact gelu
          float z = v + e0[col];
          float g = 0.5f * z * (1.f + erff(z * 0.70710678118654752f));
          ob[(size_t)row * N + col] = f2bf(g);
        }
      }
}

// ---------------- decayed attention, flash-style; i-tile 64, j-tile 128
__global__ __launch_bounds__(256) void attn_kernel(
    const unsigned short* __restrict__ Qg, const unsigned short* __restrict__ Kg,
    const unsigned short* __restrict__ Vtg, const float* __restrict__ dlg,
    unsigned short* __restrict__ attn_out) {
  __shared__ __align__(16) unsigned short Ks[128 * 72];   // K-tile (j,hd), pad 64->72
  __shared__ __align__(16) unsigned short Vts[64 * 136];  // V^T tile (hd,j), pad 128->136
  __shared__ __align__(16) unsigned short Ss[64 * 136];   // S tile (i,j) roundtrip

  const int tid = threadIdx.x;
  const int wid = tid >> 6;
  const int lane = tid & 63;
  const int ln = lane & 15;
  const int quad = lane >> 4;

  const int i0 = blockIdx.x * 64;
  const int bh = blockIdx.y;
  const int b = bh >> 3, h = bh & 7;

  const unsigned short* Qb = Qg + (size_t)bh * TT * HD;
  const unsigned short* Kb = Kg + (size_t)bh * TT * HD;
  const unsigned short* Vb = Vtg + (size_t)bh * HD * TT;

  const float logit = dlg[h];
  const float dec = 1.f / (1.f + expf(-logit));
  const float l2d = log2f(fmaxf(dec, 1e-8f));
  const bool fast = (l2d >= -1.0f);  // factorized path safe (no fp32 overflow) for d>0.5

  // Q A-fragments (rows i0+wid*16+ln), kept in regs across the j-loop
  bf16x8 qa[2];
#pragma unroll
  for (int kb = 0; kb < 2; ++kb)
    qa[kb] = frag16(Qb + (size_t)(i0 + wid * 16 + ln) * HD + kb * 32 + quad * 8);

  // per-lane decay factor tables: d^(i-i0), d^-(i-i0), d^-(j-j0), d^(j-j0)
  float rf[4], rfi[4], cf[8], cfi[8];
#pragma unroll
  for (int r = 0; r < 4; ++r) {
    float il = (float)(wid * 16 + quad * 4 + r);
    rf[r] = exp2f(l2d * il);
    rfi[r] = exp2f(-l2d * il);
  }
#pragma unroll
  for (int nb = 0; nb < 8; ++nb) {
    float jl = (float)(nb * 16 + ln);
    cf[nb] = exp2f(-l2d * jl);
    cfi[nb] = exp2f(l2d * jl);
  }

  floatx4 oacc[4];
#pragma unroll
  for (int i = 0; i < 4; ++i) oacc[i] = (floatx4){0.f, 0.f, 0.f, 0.f};
  float zacc[4] = {0.f, 0.f, 0.f, 0.f};

  for (int j0 = 0; j0 < TT; j0 += 128) {
    const int gap = i0 - j0;
    int mind = 0;
    if (gap >= 128) mind = gap - 127;
    else if (gap <= -64) mind = -gap - 63;
    if (l2d * (float)mind < -40.f) continue;  // max tile weight < 2^-40: negligible

    __syncthreads();  // previous PV reads done before restaging
#pragma unroll
    for (int r2 = 0; r2 < 4; ++r2) {
      int c = tid + r2 * 256;
      int row = c >> 3, c16 = (c & 7) * 8;
      *(uint4*)(&Ks[row * 72 + c16]) = *(const uint4*)(Kb + (size_t)(j0 + row) * HD + c16);
    }
#pragma unroll
    for (int r2 = 0; r2 < 4; ++r2) {
      int c = tid + r2 * 256;
      int row = c >> 4, c16 = (c & 15) * 8;
      *(uint4*)(&Vts[row * 136 + c16]) = *(const uint4*)(Vb + (size_t)row * TT + j0 + c16);
    }
    __syncthreads();

    const float wS = exp2f(l2d * (float)gap);    // d^(i0-j0)   (used when i>=j)
    const float wSb = exp2f(-l2d * (float)gap);  // d^(j0-i0)   (used when j>i)

#pragma unroll
    for (int nb = 0; nb < 8; ++nb) {
      floatx4 sacc = (floatx4){0.f, 0.f, 0.f, 0.f};
#pragma unroll
      for (int kb = 0; kb < 2; ++kb) {
        bf16x8 bk = frag16(&Ks[(nb * 16 + ln) * 72 + kb * 32 + quad * 8]);
        sacc = mfma_bf16(qa[kb], bk, sacc);
      }
#pragma unroll
      for (int r = 0; r < 4; ++r) {
        int il = wid * 16 + quad * 4 + r;
        int jl = nb * 16 + ln;
        int sd = gap + il - jl;  // i - j
        float w;
        if (fast)
          w = (sd >= 0) ? (wS * rf[r]) * cf[nb] : (wSb * rfi[r]) * cfi[nb];
        else
          w = exp2f(l2d * fabsf((float)sd));
        float sv = sacc[r] * w;
        zacc[r] += sv;
        Ss[(size_t)(wid * 16 + quad * 4 + r) * 136 + nb * 16 + ln] = f2bf(sv);
      }
    }
    __syncthreads();  // S visible (also orders within-wave write->read)

    bf16x8 af[4];
#pragma unroll
    for (int kb = 0; kb < 4; ++kb)
      af[kb] = frag16(&Ss[(size_t)(wid * 16 + ln) * 136 + kb * 32 + quad * 8]);
#pragma unroll
    for (int n2 = 0; n2 < 4; ++n2) {
#pragma unroll
      for (int kb = 0; kb < 4; ++kb) {
        bf16x8 bv = frag16(&Vts[(size_t)(n2 * 16 + ln) * 136 + kb * 32 + quad * 8]);
        oacc[n2] = mfma_bf16(af[kb], bv, oacc[n2]);
      }
    }
  }

  // row-sum denominator: reduce zacc across the 16 lanes of each quad
  float rz[4];
#pragma unroll
  for (int r = 0; r < 4; ++r) {
    float z = zacc[r];
    z += __shfl_xor(z, 1);
    z += __shfl_xor(z, 2);
    z += __shfl_xor(z, 4);
    z += __shfl_xor(z, 8);
    rz[r] = 1.f / fmaxf(z, 1e-6f);
  }

#pragma unroll
  for (int n2 = 0; n2 < 4; ++n2)
#pragma unroll
    for (int r = 0; r < 4; ++r) {
      int i = i0 + wid * 16 + quad * 4 + r;
      int col = h * 64 + n2 * 16 + ln;
      attn_out[(size_t)(b * TT + i) * DD + col] = f2bf(oacc[n2][r] * rz[r]);
    }
}

extern "C" void kernel_launch(void* const* d_in, const int* in_sizes, int n_in,
                              void* d_out, int out_size, void* d_ws, size_t ws_size,
                              hipStream_t stream) {
  const float* x = (const float*)d_in[0];
  const unsigned char* msk = (const unsigned char*)d_in[1];
  const float* wq = (const float*)d_in[2];
  const float* wk = (const float*)d_in[3];
  const float* wv = (const float*)d_in[4];
  const float* wo = (const float*)d_in[5];
  const float* bo = (const float*)d_in[6];
  const float* g1 = (const float*)d_in[7];
  const float* b1 = (const float*)d_in[8];
  const float* g2 = (const float*)d_in[9];
  const float* b2 = (const float*)d_in[10];
  const float* w1 = (const float*)d_in[11];
  const float* bf1 = (const float*)d_in[12];
  const float* w2 = (const float*)d_in[13];
  const float* bf2 = (const float*)d_in[14];
  const float* dlg = (const float*)d_in[15];
  float* out = (float*)d_out;

  char* p = (char*)d_ws;
  size_t off = 0;
  auto carve = [&](size_t bytes) {
    char* q = p + off;
    off += (bytes + 255) & ~(size_t)255;
    return q;
  };
  unsigned short* xn = (unsigned short*)carve((size_t)M4 * DD * 2);
  unsigned short* wqkvT = (unsigned short*)carve((size_t)1536 * DD * 2);
  unsigned short* woT = (unsigned short*)carve((size_t)DD * DD * 2);
  unsigned short* w1T = (unsigned short*)carve((size_t)FF_ * DD * 2);
  unsigned short* w2T = (unsigned short*)carve((size_t)DD * FF_ * 2);
  unsigned short* Qb = (unsigned short*)carve((size_t)16 * TT * HD * 2);
  unsigned short* Kb = (unsigned short*)carve((size_t)16 * TT * HD * 2);
  unsigned short* Vtb = (unsigned short*)carve((size_t)16 * HD * TT * 2);
  unsigned short* attn = (unsigned short*)carve((size_t)M4 * DD * 2);
  float* x2 = (float*)carve((size_t)M4 * DD * 4);
  unsigned short* xn2 = (unsigned short*)carve((size_t)M4 * DD * 2);
  unsigned short* ffh = (unsigned short*)carve((size_t)M4 * FF_ * 2);

  // weight transposes (blocks 0..3071) + LN1 (blocks 3072..5119) in one launch
  prep_kernel<<<5120, 256, 0, stream>>>(wq, wk, wv, wo, w1, w2,
                                        wqkvT, woT, w1T, w2T, x, g1, b1, xn);

  // QKV: M=4096, N=1536, K=512 — 64x128 tiles, KU=2 (24KB LDS), 768 blocks (3/CU)
  gemm_ku<64, 128, 2, 512, 0><<<dim3(M4 / 64, 1536 / 128), 256, 0, stream>>>(
      xn, wqkvT, 1536, nullptr, nullptr, nullptr, Qb, Kb, Vtb, msk);

  attn_kernel<<<dim3(TT / 64, 16), 256, 0, stream>>>(Qb, Kb, Vtb, dlg, attn);

  // out-proj: M=4096, N=512, K=512 — 64x64 tiles, KU=4 (32KB LDS), 512 blocks, 2 K-iters
  gemm_ku<64, 64, 4, 512, 1><<<dim3(M4 / 64, DD / 64), 256, 0, stream>>>(
      attn, woT, DD, bo, x, x2, nullptr, nullptr, nullptr, nullptr);

  ln_kernel<<<M4, 128, 0, stream>>>(x2, g2, b2, xn2);

  // FFN1: M=4096, N=2048, K=512 — 64x128 tiles, KU=2, 1024 blocks (4/CU)
  gemm_ku<64, 128, 2, 512, 2><<<dim3(M4 / 64, FF_ / 128), 256, 0, stream>>>(
      xn2, w1T, FF_, bf1, nullptr, nullptr, ffh, nullptr, nullptr, nullptr);

  // FFN2: M=4096, N=512, K=2048 — 64x64 tiles, KU=4, 512 blocks, 8 K-iters
  gemm_ku<64, 64, 4, 2048, 1><<<dim3(M4 / 64, DD / 64), 256, 0, stream>>>(
      ffh, w2T, DD, bf2, x2, out, nullptr, nullptr, nullptr, nullptr);
}